// Round 4
// baseline (113.012 us; speedup 1.0000x reference)
//
#include <hip/hip_runtime.h>

// make_blocks: out[b,p,a,c,:] = concat(seq1M[b, r0+c, :], seq2M[b, c0+a, :], geo[b,p,a,c])
// B=64, L=2048, D=60, P=16, PS=30 -> out [64,16,30,30,121] fp32 (446 MB).
//
// R4: R3's descriptor scheme + BANK-SWIZZLED LDS layout.
// Within a wave, same-slot ds_read addresses step 4 floats (lanes own consecutive
// float4s of the 121-periodic output) -> plain layout is an 8-way bank conflict.
// Swizzle rows/cols with perm(k) = (k&3)*15 + (k>>2) (bijection on [0,60)):
// perm(k0+4l) = perm(k0) + l -> bank stride 1 across lanes -> conflict-free.

constexpr int B_    = 64;
constexpr int L_    = 2048;
constexpr int D_    = 60;
constexpr int P_    = 16;
constexpr int PS_   = 30;
constexpr int KOUT  = 2 * D_ + 1;          // 121
constexpr int NPAIR = PS_ * PS_;           // 900
constexpr int CHUNK = NPAIR * KOUT;        // 108900 floats per (b,p)
constexpr int ROWF  = PS_ * KOUT;          // 3630 floats per 'a' row
constexpr int AP_F4 = 2 * ROWF / 4;        // 1815 float4 per a-pair stripe
constexpr int NAP   = PS_ / 2;             // 15 stripes per chunk

constexpr int NT = 512;
constexpr int NS = (AP_F4 + NT - 1) / NT;  // 4 float4 slots per thread

constexpr int RPAD  = 64;                  // swizzled row stride (floats)
constexpr int CBASE = PS_ * RPAD;          // 1920
constexpr int GBASE = 2 * CBASE;           // 3840 (geo at stride 32)
constexpr int LDSF  = GBASE + PS_ * 32;    // 4800 floats = 19.2 KB

__device__ __forceinline__ int perm60(int k) { return (k & 3) * 15 + (k >> 2); }

__global__ __launch_bounds__(NT) void make_blocks_38860864094557_kernel(
    const float* __restrict__ seq1, const float* __restrict__ seq2,
    const float* __restrict__ geo,  const int* __restrict__ patches,
    float* __restrict__ out)
{
    __shared__ float sh[LDSF];

    const int bp  = blockIdx.x;       // (b,p)
    const int b   = bp / P_;
    const int tid = threadIdx.x;

    const int r0 = patches[bp * 2 + 0];
    const int c0 = patches[bp * 2 + 1];

    const float* s1 = seq1 + ((size_t)b * L_ + r0) * D_;   // 1800 contiguous floats
    const float* s2 = seq2 + ((size_t)b * L_ + c0) * D_;
    const float* gg = geo  + (size_t)bp * NPAIR;

    // Stage: coalesced global reads, swizzled conflict-free ds_writes.
    for (int i = tid; i < PS_ * D_; i += NT) {             // 1800 each
        const int c = i / D_;                              // magic div
        const int k = i - c * D_;
        const int pa = c * RPAD + perm60(k);
        sh[pa]         = s1[i];
        sh[CBASE + pa] = s2[i];
    }
    for (int i = tid; i < NPAIR; i += NT) {                // 900
        const int a = i / PS_;
        const int c = i - a * PS_;
        sh[GBASE + a * 32 + c] = gg[i];
    }
    __syncthreads();

    // Per-thread descriptors: LDS byte offset + per-stripe byte stride for each
    // of the 4 components of each owned float4 (computed once).
    int offb[NS][4];
    int strb[NS][4];
    bool valid[NS];
#pragma unroll
    for (int s = 0; s < NS; ++s) {
        const int u4 = tid + s * NT;
        valid[s] = (u4 < AP_F4);
        const int u4c = valid[s] ? u4 : (AP_F4 - 1);
#pragma unroll
        for (int j = 0; j < 4; ++j) {
            const int u  = 4 * u4c + j;          // float index within stripe [0,7260)
            const int ah = (u >= ROWF) ? 1 : 0;  // which 'a' of the pair
            const int r  = u - ah * ROWF;        // [0,3630)
            const int c  = r / KOUT;             // magic div
            const int k  = r - c * KOUT;
            int off, st;
            if (k < D_)          { off = c * RPAD + perm60(k);                st = 0;         }
            else if (k < 2*D_)   { off = CBASE + ah * RPAD + perm60(k - D_);  st = 2 * RPAD;  }
            else                 { off = GBASE + ah * 32 + c;                 st = 2 * 32;    }
            offb[s][j] = off * 4;
            strb[s][j] = st * 4;
        }
    }

    float4* outf4 = reinterpret_cast<float4*>(out + (size_t)bp * CHUNK);
    const char* shb = reinterpret_cast<const char*>(sh);

    // 15 a-pair stripes: per thread, 4x(ds_read_b32 + add) + one dwordx4 store
    // per owned float4. Reads are bank-conflict-free by construction.
    for (int ap = 0; ap < NAP; ++ap) {
#pragma unroll
        for (int s = 0; s < NS; ++s) {
            if (valid[s]) {
                float4 v;
                v.x = *reinterpret_cast<const float*>(shb + offb[s][0]);
                v.y = *reinterpret_cast<const float*>(shb + offb[s][1]);
                v.z = *reinterpret_cast<const float*>(shb + offb[s][2]);
                v.w = *reinterpret_cast<const float*>(shb + offb[s][3]);
                outf4[ap * AP_F4 + tid + s * NT] = v;
            }
#pragma unroll
            for (int j = 0; j < 4; ++j) offb[s][j] += strb[s][j];
        }
    }
}

extern "C" void kernel_launch(void* const* d_in, const int* in_sizes, int n_in,
                              void* d_out, int out_size, void* d_ws, size_t ws_size,
                              hipStream_t stream) {
    const float* seq1    = (const float*)d_in[0];
    const float* seq2    = (const float*)d_in[1];
    const float* geo     = (const float*)d_in[2];
    const int*   patches = (const int*)d_in[3];
    float*       out     = (float*)d_out;

    const int grid = B_ * P_;   // 1024 blocks, one per (b,p); 4 blocks/CU
    make_blocks_38860864094557_kernel<<<grid, NT, 0, stream>>>(seq1, seq2, geo, patches, out);
}